// Round 1
// baseline (101.518 us; speedup 1.0000x reference)
//
#include <hip/hip_runtime.h>
#include <math.h>

// Problem constants (reference: B,S,D = 8,2048,512, all fp32)
#define B 8
#define S 2048
#define D 512

// Key algebraic identity: softmax over axis=1 (s) followed by sum over s
// makes the attention a no-op:  pooled[b,:] = sum_t r[b,t,:].
// => out[b] = sigmoid( (sum_t x[b,t,:]) . (Wl @ Wr) + S*(Wl.br) + bl )
// q/v/Wq/bq/Wv/bv are mathematically irrelevant to the output.

#define CH 64            // S-chunks per batch for the x column-sum
#define ROWS (S / CH)    // 32 rows per block
#define DCH 32           // d-row chunks for Wl@Wr
#define DROWS (D / DCH)  // 16 rows per block

__global__ void zero_ws_kernel(float* ws, int n) {
    int i = blockIdx.x * blockDim.x + threadIdx.x;
    if (i < n) ws[i] = 0.0f;
}

// xs[b*D + d] = sum_t x[b,t,d].  grid = B*CH blocks, 128 threads (float4 lanes over D).
__global__ void colsum_x_kernel(const float4* __restrict__ x, float* __restrict__ xs) {
    int blk = blockIdx.x;
    int b = blk / CH;
    int ch = blk % CH;
    int tid = threadIdx.x;  // 0..127, one float4 column each
    const float4* p = x + (size_t)(b * S + ch * ROWS) * (D / 4) + tid;
    float4 acc = {0.f, 0.f, 0.f, 0.f};
#pragma unroll
    for (int i = 0; i < ROWS; ++i) {
        float4 v = p[(size_t)i * (D / 4)];
        acc.x += v.x; acc.y += v.y; acc.z += v.z; acc.w += v.w;
    }
    float* dst = xs + b * D + tid * 4;
    atomicAdd(dst + 0, acc.x);
    atomicAdd(dst + 1, acc.y);
    atomicAdd(dst + 2, acc.z);
    atomicAdd(dst + 3, acc.w);
}

// wcomb[e] = sum_d Wl[d] * Wr[d*D + e].  grid = DCH blocks, 128 threads.
__global__ void wlwr_kernel(const float4* __restrict__ Wr, const float* __restrict__ Wl,
                            float* __restrict__ wcomb) {
    int ch = blockIdx.x;
    int tid = threadIdx.x;
    float4 acc = {0.f, 0.f, 0.f, 0.f};
#pragma unroll
    for (int i = 0; i < DROWS; ++i) {
        int d = ch * DROWS + i;
        float wl = Wl[d];
        float4 v = Wr[(size_t)d * (D / 4) + tid];
        acc.x += wl * v.x; acc.y += wl * v.y; acc.z += wl * v.z; acc.w += wl * v.w;
    }
    float* dst = wcomb + tid * 4;
    atomicAdd(dst + 0, acc.x);
    atomicAdd(dst + 1, acc.y);
    atomicAdd(dst + 2, acc.z);
    atomicAdd(dst + 3, acc.w);
}

// out[b] = sigmoid( xs[b] . wcomb + S*(Wl.br) + bl ).  1 block, 512 threads = 8 waves,
// wave w handles batch b = w.
__global__ void final_kernel(const float* __restrict__ xs, const float* __restrict__ wcomb,
                             const float* __restrict__ Wl, const float* __restrict__ br,
                             const float* __restrict__ bl, float* __restrict__ out) {
    int w = threadIdx.x >> 6;   // wave index == batch index
    int l = threadIdx.x & 63;   // lane
    float s = 0.f, wb = 0.f;
#pragma unroll
    for (int k = 0; k < D / 64; ++k) {
        int e = l + 64 * k;
        s  += xs[w * D + e] * wcomb[e];
        wb += Wl[e] * br[e];
    }
    // wave-64 butterfly reduce
#pragma unroll
    for (int off = 32; off > 0; off >>= 1) {
        s  += __shfl_down(s, off);
        wb += __shfl_down(wb, off);
    }
    if (l == 0) {
        float logit = s + (float)S * wb + bl[0];
        out[w] = 1.0f / (1.0f + expf(-logit));
    }
}

extern "C" void kernel_launch(void* const* d_in, const int* in_sizes, int n_in,
                              void* d_out, int out_size, void* d_ws, size_t ws_size,
                              hipStream_t stream) {
    // inputs: 0=x 1=Wq 2=bq 3=Wv 4=bv 5=Wr 6=br 7=Wl 8=bl (q/v path unused — see identity above)
    const float* x  = (const float*)d_in[0];
    const float* Wr = (const float*)d_in[5];
    const float* br = (const float*)d_in[6];
    const float* Wl = (const float*)d_in[7];
    const float* bl = (const float*)d_in[8];
    float* out = (float*)d_out;

    float* xs    = (float*)d_ws;   // B*D floats
    float* wcomb = xs + B * D;     // D floats
    const int ws_floats = B * D + D;  // 4608

    zero_ws_kernel<<<(ws_floats + 255) / 256, 256, 0, stream>>>((float*)d_ws, ws_floats);
    colsum_x_kernel<<<B * CH, 128, 0, stream>>>((const float4*)x, xs);
    wlwr_kernel<<<DCH, 128, 0, stream>>>((const float4*)Wr, Wl, wcomb);
    final_kernel<<<1, 512, 0, stream>>>(xs, wcomb, Wl, br, bl, out);
}

// Round 2
// 92.707 us; speedup vs baseline: 1.0950x; 1.0950x over previous
//
#include <hip/hip_runtime.h>
#include <math.h>

// Problem constants (reference: B,S,D = 8,2048,512, all fp32)
#define B 8
#define S 2048
#define D 512

// Algebraic identity: softmax over axis=1 (s) followed by emb.sum(axis=1)
// makes attention a no-op: sum_s attn[b,s,t] == 1, so pooled[b] = sum_t r[b,t,:].
//   out[b] = sigmoid( (sum_t x[b,t,:]) . (Wl @ Wr) + S*(Wl.br) + bl )
// q/v/Wq/bq/Wv/bv are mathematically irrelevant.
//
// Structure (2 kernels, no atomics, no zero-init — all ws words are overwritten):
//   stage1: blocks 0..511  -> px[b][ch][D] partial column-sums of x
//           blocks 512..543-> pw[j][D]     partials of Wl @ Wr
//   stage2: 8 blocks (one per batch) reduce partials -> logit -> sigmoid.

#define CH 64            // S-chunks per batch
#define ROWS (S / CH)    // 32 rows per block
#define WBLK 32          // Wl@Wr partial blocks
#define WROWS (D / WBLK) // 16 d-rows per block

__global__ __launch_bounds__(256) void stage1(const float4* __restrict__ x,
                                              const float4* __restrict__ Wr,
                                              const float* __restrict__ Wl,
                                              float4* __restrict__ px,   // [B*CH][D/4]
                                              float4* __restrict__ pw) { // [WBLK][D/4]
    __shared__ float4 sbuf[128];
    const int tid  = threadIdx.x;
    const int col  = tid & 127;   // float4 column 0..127 (covers D=512 floats)
    const int half = tid >> 7;    // 0/1: two rows in flight per iteration
    const int blk  = blockIdx.x;
    float4 acc = {0.f, 0.f, 0.f, 0.f};

    if (blk < B * CH) {
        const int b = blk / CH, ch = blk % CH;
        const float4* p = x + (size_t)(b * S + ch * ROWS + half) * (D / 4) + col;
#pragma unroll
        for (int i = 0; i < ROWS; i += 2) {
            float4 v = p[(size_t)i * (D / 4)];
            acc.x += v.x; acc.y += v.y; acc.z += v.z; acc.w += v.w;
        }
    } else {
        const int j = blk - B * CH;  // 0..31
#pragma unroll
        for (int i = 0; i < WROWS; i += 2) {
            int d = j * WROWS + i + half;
            float wl = Wl[d];
            float4 v = Wr[(size_t)d * (D / 4) + col];
            acc.x += wl * v.x; acc.y += wl * v.y; acc.z += wl * v.z; acc.w += wl * v.w;
        }
    }

    if (half) sbuf[col] = acc;
    __syncthreads();
    if (!half) {
        float4 o = sbuf[col];
        acc.x += o.x; acc.y += o.y; acc.z += o.z; acc.w += o.w;
        if (blk < B * CH) px[(size_t)blk * (D / 4) + col] = acc;
        else              pw[(size_t)(blk - B * CH) * (D / 4) + col] = acc;
    }
}

__global__ __launch_bounds__(512) void stage2(const float* __restrict__ px,
                                              const float* __restrict__ pw,
                                              const float* __restrict__ Wl,
                                              const float* __restrict__ br,
                                              const float* __restrict__ bl,
                                              float* __restrict__ out) {
    const int b = blockIdx.x;
    const int e = threadIdx.x;  // 0..511, one d-element each

    float wsum = 0.f;  // wcomb[e] = sum_d Wl[d]*Wr[d,e]
#pragma unroll
    for (int j = 0; j < WBLK; ++j) wsum += pw[j * D + e];

    float xsum = 0.f;  // xs[b,e] = sum_t x[b,t,e]
#pragma unroll
    for (int ch = 0; ch < CH; ++ch) xsum += px[((size_t)b * CH + ch) * D + e];

    float val = xsum * wsum;
    float wb  = Wl[e] * br[e];

    // wave-64 butterfly, then cross-wave via LDS
#pragma unroll
    for (int off = 32; off > 0; off >>= 1) {
        val += __shfl_down(val, off);
        wb  += __shfl_down(wb, off);
    }
    __shared__ float sv[8], sw[8];
    const int w = e >> 6, l = e & 63;
    if (l == 0) { sv[w] = val; sw[w] = wb; }
    __syncthreads();
    if (e == 0) {
        float v = 0.f, wbt = 0.f;
#pragma unroll
        for (int i = 0; i < 8; ++i) { v += sv[i]; wbt += sw[i]; }
        float logit = v + (float)S * wbt + bl[0];
        out[b] = 1.0f / (1.0f + expf(-logit));
    }
}

extern "C" void kernel_launch(void* const* d_in, const int* in_sizes, int n_in,
                              void* d_out, int out_size, void* d_ws, size_t ws_size,
                              hipStream_t stream) {
    // inputs: 0=x 1=Wq 2=bq 3=Wv 4=bv 5=Wr 6=br 7=Wl 8=bl (q/v path unused — identity above)
    const float* x  = (const float*)d_in[0];
    const float* Wr = (const float*)d_in[5];
    const float* br = (const float*)d_in[6];
    const float* Wl = (const float*)d_in[7];
    const float* bl = (const float*)d_in[8];
    float* out = (float*)d_out;

    float* px = (float*)d_ws;            // B*CH*D floats = 1 MB
    float* pw = px + (size_t)B * CH * D; // WBLK*D floats = 64 KB

    stage1<<<B * CH + WBLK, 256, 0, stream>>>((const float4*)x, (const float4*)Wr, Wl,
                                              (float4*)px, (float4*)pw);
    stage2<<<B, 512, 0, stream>>>(px, pw, Wl, br, bl, out);
}